// Round 5
// baseline (132.978 us; speedup 1.0000x reference)
//
#include <hip/hip_runtime.h>

#define L_ 9216

typedef unsigned int uint;
typedef unsigned short ushort;
typedef __attribute__((ext_vector_type(8))) short short8;
typedef __attribute__((ext_vector_type(4))) float f32x4;
typedef __attribute__((ext_vector_type(16))) float f32x16;
typedef __attribute__((ext_vector_type(4))) unsigned uint4v;

#define MFMA32(a, b, c) __builtin_amdgcn_mfma_f32_32x32x16_bf16(a, b, c, 0, 0, 0)

#if __has_builtin(__builtin_amdgcn_exp2f)
#define EXP2(x) __builtin_amdgcn_exp2f(x)
#else
#define EXP2(x) exp2f(x)
#endif

#define GLOAD_LDS16(g, l)                                            \
  __builtin_amdgcn_global_load_lds(                                  \
      (const __attribute__((address_space(1))) unsigned int*)(g),    \
      (__attribute__((address_space(3))) unsigned int*)(l), 16, 0, 0)

union B8 {
  uint4v u;
  short8 s;
};

__device__ __forceinline__ ushort f2bf(float f) {
  uint u = __float_as_uint(f);
  return (ushort)((u + 0x7fffu + ((u >> 16) & 1u)) >> 16);
}

__device__ __forceinline__ f32x16 zero16() {
  f32x16 v;
#pragma unroll
  for (int i = 0; i < 16; i++) v[i] = 0.f;
  return v;
}

// ---------------- projection: Q/K (l2-normalized) and V ----------------
// grid = (288, 3), 256 threads: 64 positions/block, 4 threads per position
// (channel quarters, reduced via shfl_xor 1,2). task 0=Q,1=K,2=V.
// Q is pre-scaled by log2e so attn can use exp2 directly.
__global__ __launch_bounds__(256) void proj_kernel(
    const float* __restrict__ x, const float* __restrict__ x_enc,
    const float* __restrict__ Wq, const float* __restrict__ bq,
    const float* __restrict__ Wk, const float* __restrict__ bk,
    const float* __restrict__ Wv, const float* __restrict__ bv,
    ushort* __restrict__ Qb, ushort* __restrict__ Kb, ushort* __restrict__ Vb) {
  const int task = blockIdx.y;
  const int t = threadIdx.x;
  const int quarter = t & 3;
  const int pidx = t >> 2;  // 0..63
  const int gp = blockIdx.x * 64 + pidx;
  const int b = blockIdx.x / 144;  // block-uniform (64 * 144 = 9216)
  const int p = gp - b * L_;

  const float* W;
  const float* bias;
  const float* X;
  int CC;
  if (task == 0) { W = Wq; bias = bq; X = x_enc + (size_t)b * 96 * L_; CC = 96; }
  else if (task == 1) { W = Wk; bias = bk; X = x_enc + (size_t)b * 96 * L_; CC = 96; }
  else { W = Wv; bias = bv; X = x + (size_t)b * 64 * L_; CC = 64; }

  __shared__ float Wt[96 * 64];  // W transposed: Wt[c][o]
  for (int i = t; i < CC * 64; i += 256) {
    int o = i / CC, c = i - o * CC;
    Wt[c * 64 + o] = W[i];
  }
  __syncthreads();

  const int ch = CC >> 2;  // channels per quarter (24 or 16)
  const int c0 = quarter * ch;

  float a0[64];
#pragma unroll
  for (int o = 0; o < 64; o++) a0[o] = 0.f;

#pragma unroll 4
  for (int c = 0; c < ch; c++) {
    float xv = X[(size_t)(c0 + c) * L_ + p];
    const float4* wr = (const float4*)&Wt[(c0 + c) * 64];
#pragma unroll
    for (int o4 = 0; o4 < 16; o4++) {
      float4 wv = wr[o4];
      a0[4 * o4 + 0] += wv.x * xv;
      a0[4 * o4 + 1] += wv.y * xv;
      a0[4 * o4 + 2] += wv.z * xv;
      a0[4 * o4 + 3] += wv.w * xv;
    }
  }
  // reduce across the 4 channel quarters (lanes ^1, ^2), then bias
#pragma unroll
  for (int o = 0; o < 64; o++) a0[o] += __shfl_xor(a0[o], 1);
#pragma unroll
  for (int o = 0; o < 64; o++) a0[o] += __shfl_xor(a0[o], 2);
#pragma unroll
  for (int o = 0; o < 64; o++) a0[o] += bias[o];

  if (task < 2) {
    float s0 = 0.f;
#pragma unroll
    for (int o = 0; o < 64; o++) s0 += a0[o] * a0[o];
    float i0 = 1.0f / fmaxf(sqrtf(s0), 1e-6f);
    if (task == 0) i0 *= 1.44269504f;  // fold log2e into Q
    ushort* dst = (task == 0 ? Qb : Kb);
    uint* d0 = (uint*)(dst + (size_t)gp * 64);
#pragma unroll
    for (int o2 = 0; o2 < 8; o2++) {
      int oo = quarter * 8 + o2;
      d0[oo] = (uint)f2bf(a0[2 * oo] * i0) | ((uint)f2bf(a0[2 * oo + 1] * i0) << 16);
    }
  } else {
#pragma unroll
    for (int o = 0; o < 16; o++) {
      int oo = quarter * 16 + o;
      Vb[(size_t)(b * 64 + oo) * L_ + p] = f2bf(a0[oo]);
    }
  }
}

// ---------------- flash attention, KV-split ----------------
// grid = 72*SPLIT blocks, 512 thr = 8 waves x 32 q-rows (256 q/block).
// Qb (log2e-scaled),Kb: [b][pos][64] bf16. Vb: [b][dv][pos] bf16.
// OP: [split][b][dv][L] bf16 unnormalized. LB: [split][b][L] fp32 denoms.
__global__ __launch_bounds__(512, 4) void attn_kernel(
    const ushort* __restrict__ Qb, const ushort* __restrict__ Kb,
    const ushort* __restrict__ Vb, ushort* __restrict__ OP,
    float* __restrict__ LB, int tps) {
  __shared__ __align__(16) ushort K_l[2][64 * 64];  // [buf][kv][d], swizzled
  __shared__ __align__(16) ushort V_l[2][64 * 64];  // [buf][dv][kv], swizzled

  const int nwg = gridDim.x;
  const int chunk = nwg >> 3;  // nwg = 72*SPLIT, always % 8 == 0
  const int bid = blockIdx.x;
  const int logical = (bid & 7) * chunk + (bid >> 3);
  const int split = logical / 72;
  const int qidx = logical - split * 72;
  const int b = qidx / 36;
  const int q0 = (qidx - b * 36) * 256;

  const int t = threadIdx.x;
  const int lane = t & 63;
  const int w = t >> 6;  // 0..7
  const int ql = lane & 31;
  const int hs = lane >> 5;

  const ushort* Kg = Kb + (size_t)b * L_ * 64;
  const ushort* Vg = Vb + (size_t)b * 64 * L_;

  // Q fragments: B-operand, col(q) = lane&31, k = hs*8+i per 16-chunk
  const int qrow = q0 + w * 32 + ql;
  const ushort* Qr = Qb + ((size_t)(b * L_ + qrow)) * 64 + hs * 8;
  short8 qf[4];
  qf[0] = *(const short8*)(Qr);
  qf[1] = *(const short8*)(Qr + 16);
  qf[2] = *(const short8*)(Qr + 32);
  qf[3] = *(const short8*)(Qr + 48);

  // ones A-fragment (bf16 1.0) for the denominator MFMA
  B8 onesu;
  onesu.u[0] = 0x3F803F80u;
  onesu.u[1] = 0x3F803F80u;
  onesu.u[2] = 0x3F803F80u;
  onesu.u[3] = 0x3F803F80u;

  f32x16 o[2];
  o[0] = zero16();
  o[1] = zero16();
  f32x16 od = zero16();  // denominator accumulator (all rows identical)

  // staging: 512 threads cover 512 chunks of 16B per 8KB tile -> 1 K-load +
  // 1 V-load per thread. LDS linear (wave base + lane*16B), global source
  // pre-swizzled (inverse of the read-side XOR).
  const int rr = t >> 3, pl = t & 7;
  const int psrc = (pl ^ (rr & 7)) << 3;
  const int j0base = split * tps * 64;

#define STAGE(buf, j0)                                                       \
  {                                                                          \
    GLOAD_LDS16(Kg + (size_t)(j0)*64 + rr * 64 + psrc, &K_l[buf][w * 512]);  \
    GLOAD_LDS16(Vg + (size_t)rr * L_ + (j0) + psrc, &V_l[buf][w * 512]);     \
  }

  STAGE(0, j0base);

  for (int tt = 0; tt < tps; tt++) {
    __syncthreads();  // buf[tt&1] staged; prev compute done
    if (tt + 1 < tps) STAGE((tt + 1) & 1, j0base + (tt + 1) * 64);
    const ushort* Kc = K_l[tt & 1];
    const ushort* Vc = V_l[tt & 1];

    B8 pf[4];
#pragma unroll
    for (int st = 0; st < 2; st++) {
      const int krow = st * 32 + ql;
      const int ksw = (krow & 7) << 3;
      f32x16 sa = zero16();
#pragma unroll
      for (int m = 0; m < 4; m++) {
        short8 kf = *(const short8*)&Kc[(krow * 64 + m * 16 + hs * 8) ^ ksw];
        sa = MFMA32(kf, qf[m], sa);
      }
      // Q pre-scaled by log2e -> p = exp2(sa) = e^s (fixed-max softmax; the
      // missing e^-1 scale cancels numerator/denominator). Truncate to bf16,
      // pack pairs with one v_perm_b32.
      uint Wp[8];
#pragma unroll
      for (int c = 0; c < 4; c++)
#pragma unroll
        for (int rp = 0; rp < 2; rp++) {
          int i0 = 4 * c + 2 * rp;
          float p0 = EXP2(sa[i0]);
          float p1 = EXP2(sa[i0 + 1]);
          Wp[2 * c + rp] = __builtin_amdgcn_perm(
              __float_as_uint(p1), __float_as_uint(p0), 0x07060302u);
        }
      // redistribute P across the hs halves: permlane32_swap
      // (dst-hi <-> src-lo): ra=swap(Wp[4u],Wp[4u+2]) -> fw[0]=ra[0],
      // fw[2]=ra[1].
#pragma unroll
      for (int u = 0; u < 2; u++) {
        auto ra = __builtin_amdgcn_permlane32_swap(Wp[4 * u + 0], Wp[4 * u + 2],
                                                   false, false);
        auto rb = __builtin_amdgcn_permlane32_swap(Wp[4 * u + 1], Wp[4 * u + 3],
                                                   false, false);
        uint4v fw;
        fw[0] = ra[0];
        fw[1] = rb[0];
        fw[2] = ra[1];
        fw[3] = rb[1];
        pf[st * 2 + u].u = fw;
      }
    }

    // denominator: od[*][q] += sum_kv P[kv][q] via ones-row MFMA (same
    // truncated bf16 P the PV consumes -> exactly consistent)
#pragma unroll
    for (int s = 0; s < 4; s++) od = MFMA32(onesu.s, pf[s].s, od);

    // O[dv][q] += V^T * P
#pragma unroll
    for (int dt = 0; dt < 2; dt++) {
      const int vrow = dt * 32 + ql;
      const int vsw = (vrow & 7) << 3;
#pragma unroll
      for (int s = 0; s < 4; s++) {
        short8 vf = *(const short8*)&Vc[(vrow * 64 + s * 16 + hs * 8) ^ vsw];
        o[dt] = MFMA32(vf, pf[s].s, o[dt]);
      }
    }
  }

  // epilogue: denom = od[0] (all rows identical; row 0 lives in hs==0's r=0)
  if (hs == 0) LB[(size_t)split * 2 * L_ + (size_t)b * L_ + qrow] = od[0];

  ushort* Ob = OP + (size_t)split * 2 * 64 * L_;
#pragma unroll
  for (int dt = 0; dt < 2; dt++)
#pragma unroll
    for (int r = 0; r < 16; r++) {
      int dv = dt * 32 + (r & 3) + 8 * (r >> 2) + 4 * hs;
      Ob[(size_t)(b * 64 + dv) * L_ + qrow] = f2bf(o[dt][r]);
    }
}

// ---------------- combine splits ----------------
// 8 output elements per thread. OP bf16, LB fp32.
__global__ __launch_bounds__(256) void combine_kernel(
    const ushort* __restrict__ OP, const float* __restrict__ LB,
    float* __restrict__ out, int nsplit) {
  const size_t e = ((size_t)blockIdx.x * 256 + threadIdx.x) * 8;
  const int bdv = (int)(e / L_);
  const int b = bdv >> 6;
  const int q = (int)(e % L_);
  float os[8], ls[8];
#pragma unroll
  for (int i = 0; i < 8; i++) { os[i] = 0.f; ls[i] = 0.f; }
  for (int s = 0; s < nsplit; s++) {
    uint4v pv = *(const uint4v*)(OP + (size_t)s * 2 * 64 * L_ + e);
    const float* lp = LB + (size_t)s * 2 * L_ + (size_t)b * L_ + q;
    f32x4 l0 = *(const f32x4*)(lp);
    f32x4 l1 = *(const f32x4*)(lp + 4);
#pragma unroll
    for (int i = 0; i < 4; i++) {
      os[2 * i] += __uint_as_float(pv[i] << 16);
      os[2 * i + 1] += __uint_as_float(pv[i] & 0xFFFF0000u);
      ls[i] += l0[i];
      ls[4 + i] += l1[i];
    }
  }
  float r[8];
#pragma unroll
  for (int i = 0; i < 8; i++) r[i] = os[i] / ls[i];
  *(f32x4*)(out + e) = *(const f32x4*)&r[0];
  *(f32x4*)(out + e + 4) = *(const f32x4*)&r[4];
}

extern "C" void kernel_launch(void* const* d_in, const int* in_sizes, int n_in,
                              void* d_out, int out_size, void* d_ws, size_t ws_size,
                              hipStream_t stream) {
  const float* x = (const float*)d_in[0];
  const float* x_enc = (const float*)d_in[1];
  const float* Wq = (const float*)d_in[2];
  const float* bq = (const float*)d_in[3];
  const float* Wk = (const float*)d_in[4];
  const float* bk = (const float*)d_in[5];
  const float* Wv = (const float*)d_in[6];
  const float* bv = (const float*)d_in[7];
  float* out = (float*)d_out;

  ushort* Qb = (ushort*)d_ws;
  ushort* Kb = Qb + (size_t)2 * L_ * 64;
  ushort* Vb = Kb + (size_t)2 * L_ * 64;
  const size_t qkv_bytes = (size_t)3 * 2 * L_ * 64 * 2;  // 7,077,888
  // per split: OP bf16 (2*64*L*2) + LB f32 (2*L*4)
  const size_t per_split = (size_t)2 * 64 * L_ * 2 + (size_t)2 * L_ * 4;

  int SPLIT = 16;
  while (SPLIT > 1 && qkv_bytes + (size_t)SPLIT * per_split > ws_size) SPLIT >>= 1;

  ushort* OP = (ushort*)((char*)d_ws + qkv_bytes);
  float* LB = (float*)(OP + (size_t)SPLIT * 2 * 64 * L_);

  proj_kernel<<<dim3(288, 3), 256, 0, stream>>>(x, x_enc, Wq, bq, Wk, bk, Wv, bv,
                                                Qb, Kb, Vb);
  attn_kernel<<<72 * SPLIT, 512, 0, stream>>>(Qb, Kb, Vb, OP, LB, 144 / SPLIT);
  combine_kernel<<<(2 * 64 * L_ / 8) / 256, 256, 0, stream>>>(OP, LB, out, SPLIT);
}

// Round 6
// 111.645 us; speedup vs baseline: 1.1911x; 1.1911x over previous
//
#include <hip/hip_runtime.h>

#define L_ 9216

typedef unsigned int uint;
typedef unsigned short ushort;
typedef __attribute__((ext_vector_type(8))) short short8;
typedef __attribute__((ext_vector_type(4))) float f32x4;
typedef __attribute__((ext_vector_type(16))) float f32x16;
typedef __attribute__((ext_vector_type(4))) unsigned uint4v;

#define MFMA32(a, b, c) __builtin_amdgcn_mfma_f32_32x32x16_bf16(a, b, c, 0, 0, 0)

#if __has_builtin(__builtin_amdgcn_exp2f)
#define EXP2(x) __builtin_amdgcn_exp2f(x)
#else
#define EXP2(x) exp2f(x)
#endif

#define GLOAD_LDS16(g, l)                                            \
  __builtin_amdgcn_global_load_lds(                                  \
      (const __attribute__((address_space(1))) unsigned int*)(g),    \
      (__attribute__((address_space(3))) unsigned int*)(l), 16, 0, 0)

union B8 {
  uint4v u;
  short8 s;
};

__device__ __forceinline__ ushort f2bf(float f) {
  uint u = __float_as_uint(f);
  return (ushort)((u + 0x7fffu + ((u >> 16) & 1u)) >> 16);
}

__device__ __forceinline__ f32x16 zero16() {
  f32x16 v;
#pragma unroll
  for (int i = 0; i < 16; i++) v[i] = 0.f;
  return v;
}

// Software-pipelined column GEMM: NCH chunks of 8 channels. Next chunk's 8
// independent global loads are issued before computing the current chunk
// (double-buffered registers, all indices compile-time).
template <int NCH>
__device__ __forceinline__ void gemm_cols(const float* __restrict__ Xp,
                                          const float* __restrict__ WtBase,
                                          float* a0) {
  float xa[8], xb[8];
#pragma unroll
  for (int j = 0; j < 8; j++) xa[j] = Xp[(size_t)j * L_];
#pragma unroll
  for (int ck = 0; ck < NCH; ck++) {
    float* cur = (ck & 1) ? xb : xa;
    float* nxt = (ck & 1) ? xa : xb;
    if (ck + 1 < NCH) {
#pragma unroll
      for (int j = 0; j < 8; j++)
        nxt[j] = Xp[(size_t)((ck + 1) * 8 + j) * L_];
    }
#pragma unroll
    for (int j = 0; j < 8; j++) {
      const float4* wr = (const float4*)(WtBase + (ck * 8 + j) * 64);
      float xv = cur[j];
#pragma unroll
      for (int o4 = 0; o4 < 16; o4++) {
        float4 wv = wr[o4];
        a0[4 * o4 + 0] += wv.x * xv;
        a0[4 * o4 + 1] += wv.y * xv;
        a0[4 * o4 + 2] += wv.z * xv;
        a0[4 * o4 + 3] += wv.w * xv;
      }
    }
  }
}

// ---------------- projection: Q/K (l2-normalized) and V ----------------
// grid = (144, 3), 256 threads: 128 positions/block, 2 threads per position
// (channel halves, pair-reduced via shfl_xor(1) -> DPP). task 0=Q,1=K,2=V.
// Q is pre-scaled by log2e so attn can use exp2 directly.
__global__ __launch_bounds__(256) void proj_kernel(
    const float* __restrict__ x, const float* __restrict__ x_enc,
    const float* __restrict__ Wq, const float* __restrict__ bq,
    const float* __restrict__ Wk, const float* __restrict__ bk,
    const float* __restrict__ Wv, const float* __restrict__ bv,
    ushort* __restrict__ Qb, ushort* __restrict__ Kb, ushort* __restrict__ Vb) {
  const int task = blockIdx.y;
  const int t = threadIdx.x;
  const int half = t & 1;
  const int pidx = t >> 1;  // 0..127
  const int gp = blockIdx.x * 128 + pidx;
  const int b = (blockIdx.x * 128) / L_;  // block-uniform (128 | 9216)
  const int p = gp - b * L_;

  const float* W;
  const float* bias;
  const float* X;
  int CC;
  if (task == 0) { W = Wq; bias = bq; X = x_enc + (size_t)b * 96 * L_; CC = 96; }
  else if (task == 1) { W = Wk; bias = bk; X = x_enc + (size_t)b * 96 * L_; CC = 96; }
  else { W = Wv; bias = bv; X = x + (size_t)b * 64 * L_; CC = 64; }

  __shared__ float Wt[96 * 64];  // W transposed: Wt[c][o]
  for (int i = t; i < CC * 64; i += 256) {
    int o = i / CC, c = i - o * CC;
    Wt[c * 64 + o] = W[i];
  }
  __syncthreads();

  const int ch = CC >> 1;  // channels per half: 48 (Q/K) or 32 (V)
  const int c0 = half * ch;

  float a0[64];
#pragma unroll
  for (int o = 0; o < 64; o++) a0[o] = 0.f;

  const float* Xp = X + (size_t)c0 * L_ + p;
  const float* WtBase = &Wt[c0 * 64];
  if (ch == 48)
    gemm_cols<6>(Xp, WtBase, a0);
  else
    gemm_cols<4>(Xp, WtBase, a0);

  // pair-reduce across channel halves (lane^1), then bias
#pragma unroll
  for (int o = 0; o < 64; o++) a0[o] += __shfl_xor(a0[o], 1);
#pragma unroll
  for (int o = 0; o < 64; o++) a0[o] += bias[o];

  if (task < 2) {
    float s0 = 0.f;
#pragma unroll
    for (int o = 0; o < 64; o++) s0 += a0[o] * a0[o];
    float i0 = 1.0f / fmaxf(sqrtf(s0), 1e-6f);
    if (task == 0) i0 *= 1.44269504f;  // fold log2e into Q
    ushort* dst = (task == 0 ? Qb : Kb);
    uint* d0 = (uint*)(dst + (size_t)gp * 64);
#pragma unroll
    for (int o2 = 0; o2 < 16; o2++) {
      int oo = half * 16 + o2;
      d0[oo] = (uint)f2bf(a0[2 * oo] * i0) | ((uint)f2bf(a0[2 * oo + 1] * i0) << 16);
    }
  } else {
#pragma unroll
    for (int o = 0; o < 32; o++) {
      int oo = half * 32 + o;
      Vb[(size_t)(b * 64 + oo) * L_ + p] = f2bf(a0[oo]);
    }
  }
}

// ---------------- flash attention, KV-split ----------------
// grid = 72*SPLIT blocks, 512 thr = 8 waves x 32 q-rows (256 q/block).
// Qb (log2e-scaled),Kb: [b][pos][64] bf16. Vb: [b][dv][pos] bf16.
// OP: [split][b][dv][L] bf16 unnormalized. LB: [split][b][L] fp32 denoms.
__global__ __launch_bounds__(512, 4) void attn_kernel(
    const ushort* __restrict__ Qb, const ushort* __restrict__ Kb,
    const ushort* __restrict__ Vb, ushort* __restrict__ OP,
    float* __restrict__ LB, int tps) {
  __shared__ __align__(16) ushort K_l[2][64 * 64];  // [buf][kv][d], swizzled
  __shared__ __align__(16) ushort V_l[2][64 * 64];  // [buf][dv][kv], swizzled

  const int nwg = gridDim.x;
  const int chunk = nwg >> 3;  // nwg = 72*SPLIT, always % 8 == 0
  const int bid = blockIdx.x;
  const int logical = (bid & 7) * chunk + (bid >> 3);
  const int split = logical / 72;
  const int qidx = logical - split * 72;
  const int b = qidx / 36;
  const int q0 = (qidx - b * 36) * 256;

  const int t = threadIdx.x;
  const int lane = t & 63;
  const int w = t >> 6;  // 0..7
  const int ql = lane & 31;
  const int hs = lane >> 5;

  const ushort* Kg = Kb + (size_t)b * L_ * 64;
  const ushort* Vg = Vb + (size_t)b * 64 * L_;

  // Q fragments: B-operand, col(q) = lane&31, k = hs*8+i per 16-chunk
  const int qrow = q0 + w * 32 + ql;
  const ushort* Qr = Qb + ((size_t)(b * L_ + qrow)) * 64 + hs * 8;
  short8 qf[4];
  qf[0] = *(const short8*)(Qr);
  qf[1] = *(const short8*)(Qr + 16);
  qf[2] = *(const short8*)(Qr + 32);
  qf[3] = *(const short8*)(Qr + 48);

  // ones A-fragment (bf16 1.0) for the denominator MFMA
  B8 onesu;
  onesu.u[0] = 0x3F803F80u;
  onesu.u[1] = 0x3F803F80u;
  onesu.u[2] = 0x3F803F80u;
  onesu.u[3] = 0x3F803F80u;

  f32x16 o[2];
  o[0] = zero16();
  o[1] = zero16();
  f32x16 od = zero16();  // denominator accumulator (all rows identical)

  // staging: 512 threads cover 512 chunks of 16B per 8KB tile -> 1 K-load +
  // 1 V-load per thread. LDS linear (wave base + lane*16B), global source
  // pre-swizzled (inverse of the read-side XOR).
  const int rr = t >> 3, pl = t & 7;
  const int psrc = (pl ^ (rr & 7)) << 3;
  const int j0base = split * tps * 64;

#define STAGE(buf, j0)                                                       \
  {                                                                          \
    GLOAD_LDS16(Kg + (size_t)(j0)*64 + rr * 64 + psrc, &K_l[buf][w * 512]);  \
    GLOAD_LDS16(Vg + (size_t)rr * L_ + (j0) + psrc, &V_l[buf][w * 512]);     \
  }

  STAGE(0, j0base);

  for (int tt = 0; tt < tps; tt++) {
    __syncthreads();  // buf[tt&1] staged; prev compute done
    if (tt + 1 < tps) STAGE((tt + 1) & 1, j0base + (tt + 1) * 64);
    const ushort* Kc = K_l[tt & 1];
    const ushort* Vc = V_l[tt & 1];

    B8 pf[4];
#pragma unroll
    for (int st = 0; st < 2; st++) {
      const int krow = st * 32 + ql;
      const int ksw = (krow & 7) << 3;
      f32x16 sa = zero16();
#pragma unroll
      for (int m = 0; m < 4; m++) {
        short8 kf = *(const short8*)&Kc[(krow * 64 + m * 16 + hs * 8) ^ ksw];
        sa = MFMA32(kf, qf[m], sa);
      }
      // Q pre-scaled by log2e -> p = exp2(sa) = e^s (fixed-max softmax; the
      // missing e^-1 scale cancels numerator/denominator). Truncate to bf16,
      // pack pairs with one v_perm_b32.
      uint Wp[8];
#pragma unroll
      for (int c = 0; c < 4; c++)
#pragma unroll
        for (int rp = 0; rp < 2; rp++) {
          int i0 = 4 * c + 2 * rp;
          float p0 = EXP2(sa[i0]);
          float p1 = EXP2(sa[i0 + 1]);
          Wp[2 * c + rp] = __builtin_amdgcn_perm(
              __float_as_uint(p1), __float_as_uint(p0), 0x07060302u);
        }
      // redistribute P across the hs halves: permlane32_swap
      // (dst-hi <-> src-lo): ra=swap(Wp[4u],Wp[4u+2]) -> fw[0]=ra[0],
      // fw[2]=ra[1].
#pragma unroll
      for (int u = 0; u < 2; u++) {
        auto ra = __builtin_amdgcn_permlane32_swap(Wp[4 * u + 0], Wp[4 * u + 2],
                                                   false, false);
        auto rb = __builtin_amdgcn_permlane32_swap(Wp[4 * u + 1], Wp[4 * u + 3],
                                                   false, false);
        uint4v fw;
        fw[0] = ra[0];
        fw[1] = rb[0];
        fw[2] = ra[1];
        fw[3] = rb[1];
        pf[st * 2 + u].u = fw;
      }
    }

    // denominator: od[*][q] += sum_kv P[kv][q] via ones-row MFMA (same
    // truncated bf16 P the PV consumes -> exactly consistent)
#pragma unroll
    for (int s = 0; s < 4; s++) od = MFMA32(onesu.s, pf[s].s, od);

    // O[dv][q] += V^T * P
#pragma unroll
    for (int dt = 0; dt < 2; dt++) {
      const int vrow = dt * 32 + ql;
      const int vsw = (vrow & 7) << 3;
#pragma unroll
      for (int s = 0; s < 4; s++) {
        short8 vf = *(const short8*)&Vc[(vrow * 64 + s * 16 + hs * 8) ^ vsw];
        o[dt] = MFMA32(vf, pf[s].s, o[dt]);
      }
    }
  }

  // epilogue: denom = od[0] (all rows identical; row 0 lives in hs==0's r=0)
  if (hs == 0) LB[(size_t)split * 2 * L_ + (size_t)b * L_ + qrow] = od[0];

  ushort* Ob = OP + (size_t)split * 2 * 64 * L_;
#pragma unroll
  for (int dt = 0; dt < 2; dt++)
#pragma unroll
    for (int r = 0; r < 16; r++) {
      int dv = dt * 32 + (r & 3) + 8 * (r >> 2) + 4 * hs;
      Ob[(size_t)(b * 64 + dv) * L_ + qrow] = f2bf(o[dt][r]);
    }
}

// ---------------- combine splits ----------------
// 8 output elements per thread. OP bf16, LB fp32.
__global__ __launch_bounds__(256) void combine_kernel(
    const ushort* __restrict__ OP, const float* __restrict__ LB,
    float* __restrict__ out, int nsplit) {
  const size_t e = ((size_t)blockIdx.x * 256 + threadIdx.x) * 8;
  const int bdv = (int)(e / L_);
  const int b = bdv >> 6;
  const int q = (int)(e % L_);
  float os[8], ls[8];
#pragma unroll
  for (int i = 0; i < 8; i++) { os[i] = 0.f; ls[i] = 0.f; }
  for (int s = 0; s < nsplit; s++) {
    uint4v pv = *(const uint4v*)(OP + (size_t)s * 2 * 64 * L_ + e);
    const float* lp = LB + (size_t)s * 2 * L_ + (size_t)b * L_ + q;
    f32x4 l0 = *(const f32x4*)(lp);
    f32x4 l1 = *(const f32x4*)(lp + 4);
#pragma unroll
    for (int i = 0; i < 4; i++) {
      os[2 * i] += __uint_as_float(pv[i] << 16);
      os[2 * i + 1] += __uint_as_float(pv[i] & 0xFFFF0000u);
      ls[i] += l0[i];
      ls[4 + i] += l1[i];
    }
  }
  float r[8];
#pragma unroll
  for (int i = 0; i < 8; i++) r[i] = os[i] / ls[i];
  *(f32x4*)(out + e) = *(const f32x4*)&r[0];
  *(f32x4*)(out + e + 4) = *(const f32x4*)&r[4];
}

extern "C" void kernel_launch(void* const* d_in, const int* in_sizes, int n_in,
                              void* d_out, int out_size, void* d_ws, size_t ws_size,
                              hipStream_t stream) {
  const float* x = (const float*)d_in[0];
  const float* x_enc = (const float*)d_in[1];
  const float* Wq = (const float*)d_in[2];
  const float* bq = (const float*)d_in[3];
  const float* Wk = (const float*)d_in[4];
  const float* bk = (const float*)d_in[5];
  const float* Wv = (const float*)d_in[6];
  const float* bv = (const float*)d_in[7];
  float* out = (float*)d_out;

  ushort* Qb = (ushort*)d_ws;
  ushort* Kb = Qb + (size_t)2 * L_ * 64;
  ushort* Vb = Kb + (size_t)2 * L_ * 64;
  const size_t qkv_bytes = (size_t)3 * 2 * L_ * 64 * 2;  // 7,077,888
  // per split: OP bf16 (2*64*L*2) + LB f32 (2*L*4)
  const size_t per_split = (size_t)2 * 64 * L_ * 2 + (size_t)2 * L_ * 4;

  int SPLIT = 16;
  while (SPLIT > 1 && qkv_bytes + (size_t)SPLIT * per_split > ws_size) SPLIT >>= 1;

  ushort* OP = (ushort*)((char*)d_ws + qkv_bytes);
  float* LB = (float*)(OP + (size_t)SPLIT * 2 * 64 * L_);

  proj_kernel<<<dim3(144, 3), 256, 0, stream>>>(x, x_enc, Wq, bq, Wk, bk, Wv, bv,
                                                Qb, Kb, Vb);
  attn_kernel<<<72 * SPLIT, 512, 0, stream>>>(Qb, Kb, Vb, OP, LB, 144 / SPLIT);
  combine_kernel<<<(2 * 64 * L_ / 8) / 256, 256, 0, stream>>>(OP, LB, out, SPLIT);
}